// Round 14
// baseline (152.958 us; speedup 1.0000x reference)
//
#include <hip/hip_runtime.h>

#define M_NODES 20000
#define N_EDGES_C 320000
#define DIM 512

typedef __attribute__((ext_vector_type(4))) float f32x4;
typedef __attribute__((ext_vector_type(4))) __bf16 bf16x4;
typedef __attribute__((ext_vector_type(8))) __bf16 bf16x8;

// ---------------- 0. zero counts ----------------
__global__ __launch_bounds__(256) void zero_k(int4* __restrict__ counts4) {
  const int i = blockIdx.x * 256 + threadIdx.x;
  if (i < M_NODES / 4) counts4[i] = int4{0, 0, 0, 0};
}

// ---------------- 1. pre_k: convert + W-transpose + degree count ------------
// R12 lesson: NO __threadfence here (G16: device-scope fence = L2 writeback
// storm on non-coherent XCDs, ~200us for 2048 blocks).
__global__ __launch_bounds__(256) void pre_k(const float* __restrict__ h,
                                             const float* __restrict__ w,
                                             const float* __restrict__ norm,
                                             const int* __restrict__ dst,
                                             __bf16* __restrict__ hb,
                                             __bf16* __restrict__ wT,
                                             int* __restrict__ counts) {
  const int bid = blockIdx.x;
  const int tid = threadIdx.x;
  const int gtid = bid * 256 + tid;
  const int gsz = gridDim.x * 256;

  // convert: hb = bf16(norm[row] * h), grid-stride over 2.56M float4 groups
  for (int i = gtid; i < M_NODES * DIM / 4; i += gsz) {
    const int elem = i * 4;
    const float s = norm[elem >> 9];
    f32x4 v = *(const f32x4*)&h[elem];
    bf16x4 o;
    o.x = (__bf16)(v.x * s);
    o.y = (__bf16)(v.y * s);
    o.z = (__bf16)(v.z * s);
    o.w = (__bf16)(v.w * s);
    *(bf16x4*)&hb[elem] = o;
  }

  // weight transpose: blocks 0..255 handle one 32x32 tile each
  if (bid < 256) {
    __shared__ float tile[32][33];
    const int bx = (bid & 15) * 32, by = (bid >> 4) * 32;
    const int tx = tid & 31, ty8 = tid >> 5;
#pragma unroll
    for (int st = 0; st < 4; ++st) {
      const int r = ty8 + st * 8;
      tile[r][tx] = w[(by + r) * DIM + bx + tx];
    }
    __syncthreads();
#pragma unroll
    for (int st = 0; st < 4; ++st) {
      const int r = ty8 + st * 8;
      wT[(bx + r) * DIM + by + tx] = (__bf16)tile[tx][r];
    }
  }

  // degree count
  for (int e = gtid; e < N_EDGES_C; e += gsz) atomicAdd(&counts[dst[e]], 1);
}

// ---------------- 2. scan: 1 block, 250 threads x 80 elements ----------------
__global__ __launch_bounds__(256) void scan_k(int* __restrict__ counts,
                                              int* __restrict__ offsets) {
  __shared__ int wsum2[4];
  const int tid = threadIdx.x;
  const int lane = tid & 63, wid = tid >> 6;
  const int base = tid * 80;
  int s = 0;
  if (tid < 250) {
#pragma unroll
    for (int i = 0; i < 80; i += 4) {
      int4 c = *(const int4*)&counts[base + i];
      s += c.x + c.y + c.z + c.w;
    }
  }
  int x = s;
#pragma unroll
  for (int off = 1; off < 64; off <<= 1) {
    int t = __shfl_up(x, off, 64);
    if (lane >= off) x += t;
  }
  if (lane == 63) wsum2[wid] = x;
  __syncthreads();
  int wbase = 0;
  for (int wI = 0; wI < wid; ++wI) wbase += wsum2[wI];
  int run = wbase + x - s;
  if (tid < 250) {
#pragma unroll
    for (int i = 0; i < 80; i += 4) {
      int4 c = *(const int4*)&counts[base + i];
      int4 o;
      o.x = run;
      o.y = run + c.x;
      o.z = o.y + c.y;
      o.w = o.z + c.z;
      *(int4*)&offsets[base + i] = o;
      *(int4*)&counts[base + i] = o;       // counts becomes fill cursor
      run = o.w + c.w;
    }
  }
  if (tid == 0) {
    int tot = 0;
#pragma unroll
    for (int wI = 0; wI < 4; ++wI) tot += wsum2[wI];
    offsets[M_NODES] = tot;
  }
}

// ---------------- 3. CSR fill ----------------
__global__ __launch_bounds__(256) void fill_k(const int* __restrict__ src,
                                              const int* __restrict__ dst,
                                              int* __restrict__ cursor,
                                              int* __restrict__ esrc) {
  int e = blockIdx.x * 256 + threadIdx.x;
  if (e < N_EDGES_C) {
    int p = atomicAdd(&cursor[dst[e]], 1);
    esrc[p] = src[e];
  }
}

// ---------------- 4. aggregate: XCD-pinned panels, 8-wide idx broadcast -----
// UNCHANGED.
__global__ __launch_bounds__(256) void aggregate_k(const __bf16* __restrict__ hb,
                                                   const int* __restrict__ offs,
                                                   const int* __restrict__ esrc,
                                                   __bf16* __restrict__ aggb) {
  const int panel = blockIdx.x & 7;           // -> XCD id (round-robin dispatch)
  const int nb = blockIdx.x >> 3;             // 0..624
  const int wv = threadIdx.x >> 6;
  const int lane = threadIdx.x & 63;
  const int slot = lane >> 3;                 // 0..7: node sub-index within wave
  const int cg = lane & 7;                    // 0..7: column group (8 cols)
  const int node = nb * 32 + wv * 8 + slot;   // 625*32 = 20000 exactly

  const int beg = offs[node], end = offs[node + 1];
  const size_t pbase = (size_t)panel * 64 + cg * 8;

  float a[8] = {};
  int j = beg;
  while (j + 8 <= end) {
    const int idx = esrc[j + cg];             // 8 consecutive indices per group
    int sid[8];
#pragma unroll
    for (int g = 0; g < 8; ++g) sid[g] = __shfl(idx, (lane & 56) + g, 64);
    bf16x8 v[8];
#pragma unroll
    for (int g = 0; g < 8; ++g)
      v[g] = *(const bf16x8*)&hb[(size_t)sid[g] * DIM + pbase];
#pragma unroll
    for (int g = 0; g < 8; ++g)
#pragma unroll
      for (int q = 0; q < 8; ++q) a[q] += (float)v[g][q];
    j += 8;
  }
  for (; j < end; ++j) {
    const int s0 = esrc[j];
    bf16x8 v0 = *(const bf16x8*)&hb[(size_t)s0 * DIM + pbase];
#pragma unroll
    for (int q = 0; q < 8; ++q) a[q] += (float)v0[q];
  }
  bf16x8 o;
#pragma unroll
  for (int q = 0; q < 8; ++q) o[q] = (__bf16)a[q];
  *(bf16x8*)&aggb[(size_t)node * DIM + pbase] = o;
}

// ---------------- 5. GEMM v6: LDS-FREE direct-from-L2 ----------------------
// R13 post-mortem: v3=v4=v5=38us regardless of schedule; MfmaUtil+VALUBusy
// = 16%, occupancy 14% -> the LDS/barrier structure itself starves the CU
// (2 blocks/CU, all waves drain together). B = 0.5 MB (L2-resident on every
// XCD), A = 20.5 MB (L3-resident): staging through LDS buys ~nothing here.
// v6: load MFMA fragments DIRECTLY from global (bf16x8/lane; a wave's
// fragment = 16 rows x 64B segments, coalesced, L2-served). No LDS, no
// barriers -> occupancy VGPR-limited, latency hidden by TLP.
__global__ __launch_bounds__(256) void gemm_k(const __bf16* __restrict__ A,
                                              const __bf16* __restrict__ B,
                                              const float* __restrict__ bias,
                                              const float* __restrict__ norm,
                                              float* __restrict__ C) {
  const int tid = threadIdx.x;
  const int lane = tid & 63;
  const int wv = tid >> 6;          // 4 waves: wr in {0,1} x wc in {0,1}
  const int wr = wv >> 1, wc = wv & 1;
  const int m0 = blockIdx.x * 64;
  const int n0 = blockIdx.y * 128;

  f32x4 acc[2][4] = {};

  // per-lane row bases (clamped A row; garbage rows masked at store)
  const int lr = lane & 15;              // row-in-fragment
  const int kc = (lane >> 4) * 8;        // k-offset within 32-wide K slice
  int arow0 = m0 + wr * 32 + lr;
  int arow1 = arow0 + 16;
  arow0 = arow0 < M_NODES ? arow0 : (M_NODES - 1);
  arow1 = arow1 < M_NODES ? arow1 : (M_NODES - 1);
  const __bf16* __restrict__ a0 = A + (size_t)arow0 * DIM + kc;
  const __bf16* __restrict__ a1 = A + (size_t)arow1 * DIM + kc;
  const __bf16* __restrict__ b0 = B + (size_t)(n0 + wc * 64 + lr) * DIM + kc;

  for (int kt = 0; kt < DIM; kt += 32) {
    bf16x8 af[2], bfr[4];
    af[0] = *(const bf16x8*)(a0 + kt);
    af[1] = *(const bf16x8*)(a1 + kt);
#pragma unroll
    for (int n = 0; n < 4; ++n)
      bfr[n] = *(const bf16x8*)(b0 + (size_t)n * 16 * DIM + kt);
#pragma unroll
    for (int m = 0; m < 2; ++m)
#pragma unroll
      for (int n = 0; n < 4; ++n)
        acc[m][n] = __builtin_amdgcn_mfma_f32_16x16x32_bf16(af[m], bfr[n], acc[m][n], 0, 0, 0);
  }

  // epilogue: C row = (lane>>4)*4 + reg, col = lane&15 within each 16x16 frag
#pragma unroll
  for (int m = 0; m < 2; ++m) {
    const int rbase = m0 + wr * 32 + m * 16 + (lane >> 4) * 4;
#pragma unroll
    for (int r = 0; r < 4; ++r) {
      const int row = rbase + r;
      if (row < M_NODES) {
        const float nv = norm[row];
#pragma unroll
        for (int n = 0; n < 4; ++n) {
          const int col = n0 + wc * 64 + n * 16 + (lane & 15);
          float v = acc[m][n][r] * nv + bias[col];
          C[(size_t)row * DIM + col] = v > 0.f ? v : 0.f;
        }
      }
    }
  }
}

// ---------------- workspace layout ----------------
#define HB_OFF   0UL                     // 20,480,000 B  bf16 h*norm
#define AGG_OFF  20480000UL              // 20,480,000 B  bf16 aggregate
#define WT_OFF   40960000UL              //    524,288 B  bf16 W^T
#define CNT_OFF  41484288UL              //     80,000 B  counts -> cursor (16B aligned)
#define OFS_OFF  41564288UL              //     80,256 B  offsets[20001]
#define ESRC_OFF 41644544UL              //  1,280,000 B  CSR src indices
#define WS_NEEDED 42924544UL

extern "C" void kernel_launch(void* const* d_in, const int* in_sizes, int n_in,
                              void* d_out, int out_size, void* d_ws, size_t ws_size,
                              hipStream_t stream) {
  const float* h    = (const float*)d_in[0];
  const float* w    = (const float*)d_in[1];
  const float* bias = (const float*)d_in[2];
  const float* norm = (const float*)d_in[3];
  const int*   src  = (const int*)d_in[4];
  const int*   dst  = (const int*)d_in[5];
  float* out = (float*)d_out;

  if (ws_size < WS_NEEDED) return;  // clean failure signal instead of OOB

  char* ws = (char*)d_ws;
  __bf16* hb      = (__bf16*)(ws + HB_OFF);
  __bf16* aggb    = (__bf16*)(ws + AGG_OFF);
  __bf16* wT      = (__bf16*)(ws + WT_OFF);
  int*    counts  = (int*)(ws + CNT_OFF);
  int*    offsets = (int*)(ws + OFS_OFF);
  int*    esrc    = (int*)(ws + ESRC_OFF);

  zero_k<<<20, 256, 0, stream>>>((int4*)counts);
  pre_k<<<2048, 256, 0, stream>>>(h, w, norm, dst, hb, wT, counts);
  scan_k<<<1, 256, 0, stream>>>(counts, offsets);
  fill_k<<<1250, 256, 0, stream>>>(src, dst, counts, esrc);
  aggregate_k<<<5000, 256, 0, stream>>>(hb, offsets, esrc, aggb);
  gemm_k<<<dim3(313, 4), 256, 0, stream>>>(aggb, wT, bias, norm, out);
}

// Round 15
// 133.495 us; speedup vs baseline: 1.1458x; 1.1458x over previous
//
#include <hip/hip_runtime.h>

#define M_NODES 20000
#define N_EDGES_C 320000
#define DIM 512

typedef __attribute__((ext_vector_type(4))) float f32x4;
typedef __attribute__((ext_vector_type(4))) __bf16 bf16x4;
typedef __attribute__((ext_vector_type(8))) __bf16 bf16x8;

// ---------------- async global->LDS (16B per lane) ----------------
__device__ __forceinline__ void async16(__bf16* lds, const __bf16* g) {
  __builtin_amdgcn_global_load_lds(
      (const __attribute__((address_space(1))) void*)g,
      (__attribute__((address_space(3))) void*)lds, 16, 0, 0);
}

// ---------------- 0. zero counts ----------------
__global__ __launch_bounds__(256) void zero_k(int4* __restrict__ counts4) {
  const int i = blockIdx.x * 256 + threadIdx.x;
  if (i < M_NODES / 4) counts4[i] = int4{0, 0, 0, 0};
}

// ---------------- 1. pre_k: convert + W-transpose + degree count ------------
// R12 lesson: NO __threadfence (G16 fence = L2 writeback storm, ~200us).
__global__ __launch_bounds__(256) void pre_k(const float* __restrict__ h,
                                             const float* __restrict__ w,
                                             const float* __restrict__ norm,
                                             const int* __restrict__ dst,
                                             __bf16* __restrict__ hb,
                                             __bf16* __restrict__ wT,
                                             int* __restrict__ counts) {
  const int bid = blockIdx.x;
  const int tid = threadIdx.x;
  const int gtid = bid * 256 + tid;
  const int gsz = gridDim.x * 256;

  for (int i = gtid; i < M_NODES * DIM / 4; i += gsz) {
    const int elem = i * 4;
    const float s = norm[elem >> 9];
    f32x4 v = *(const f32x4*)&h[elem];
    bf16x4 o;
    o.x = (__bf16)(v.x * s);
    o.y = (__bf16)(v.y * s);
    o.z = (__bf16)(v.z * s);
    o.w = (__bf16)(v.w * s);
    *(bf16x4*)&hb[elem] = o;
  }

  if (bid < 256) {
    __shared__ float tile[32][33];
    const int bx = (bid & 15) * 32, by = (bid >> 4) * 32;
    const int tx = tid & 31, ty8 = tid >> 5;
#pragma unroll
    for (int st = 0; st < 4; ++st) {
      const int r = ty8 + st * 8;
      tile[r][tx] = w[(by + r) * DIM + bx + tx];
    }
    __syncthreads();
#pragma unroll
    for (int st = 0; st < 4; ++st) {
      const int r = ty8 + st * 8;
      wT[(bx + r) * DIM + by + tx] = (__bf16)tile[tx][r];
    }
  }

  for (int e = gtid; e < N_EDGES_C; e += gsz) atomicAdd(&counts[dst[e]], 1);
}

// ---------------- 2. scan: 1 block, 250 threads x 80 elements ----------------
__global__ __launch_bounds__(256) void scan_k(int* __restrict__ counts,
                                              int* __restrict__ offsets) {
  __shared__ int wsum2[4];
  const int tid = threadIdx.x;
  const int lane = tid & 63, wid = tid >> 6;
  const int base = tid * 80;
  int s = 0;
  if (tid < 250) {
#pragma unroll
    for (int i = 0; i < 80; i += 4) {
      int4 c = *(const int4*)&counts[base + i];
      s += c.x + c.y + c.z + c.w;
    }
  }
  int x = s;
#pragma unroll
  for (int off = 1; off < 64; off <<= 1) {
    int t = __shfl_up(x, off, 64);
    if (lane >= off) x += t;
  }
  if (lane == 63) wsum2[wid] = x;
  __syncthreads();
  int wbase = 0;
  for (int wI = 0; wI < wid; ++wI) wbase += wsum2[wI];
  int run = wbase + x - s;
  if (tid < 250) {
#pragma unroll
    for (int i = 0; i < 80; i += 4) {
      int4 c = *(const int4*)&counts[base + i];
      int4 o;
      o.x = run;
      o.y = run + c.x;
      o.z = o.y + c.y;
      o.w = o.z + c.z;
      *(int4*)&offsets[base + i] = o;
      *(int4*)&counts[base + i] = o;       // counts becomes fill cursor
      run = o.w + c.w;
    }
  }
  if (tid == 0) {
    int tot = 0;
#pragma unroll
    for (int wI = 0; wI < 4; ++wI) tot += wsum2[wI];
    offsets[M_NODES] = tot;
  }
}

// ---------------- 3. CSR fill ----------------
__global__ __launch_bounds__(256) void fill_k(const int* __restrict__ src,
                                              const int* __restrict__ dst,
                                              int* __restrict__ cursor,
                                              int* __restrict__ esrc) {
  int e = blockIdx.x * 256 + threadIdx.x;
  if (e < N_EDGES_C) {
    int p = atomicAdd(&cursor[dst[e]], 1);
    esrc[p] = src[e];
  }
}

// ---------------- 4. aggregate: XCD-pinned panels, 8-wide idx broadcast -----
// UNCHANGED.
__global__ __launch_bounds__(256) void aggregate_k(const __bf16* __restrict__ hb,
                                                   const int* __restrict__ offs,
                                                   const int* __restrict__ esrc,
                                                   __bf16* __restrict__ aggb) {
  const int panel = blockIdx.x & 7;           // -> XCD id (round-robin dispatch)
  const int nb = blockIdx.x >> 3;             // 0..624
  const int wv = threadIdx.x >> 6;
  const int lane = threadIdx.x & 63;
  const int slot = lane >> 3;                 // 0..7: node sub-index within wave
  const int cg = lane & 7;                    // 0..7: column group (8 cols)
  const int node = nb * 32 + wv * 8 + slot;   // 625*32 = 20000 exactly

  const int beg = offs[node], end = offs[node + 1];
  const size_t pbase = (size_t)panel * 64 + cg * 8;

  float a[8] = {};
  int j = beg;
  while (j + 8 <= end) {
    const int idx = esrc[j + cg];             // 8 consecutive indices per group
    int sid[8];
#pragma unroll
    for (int g = 0; g < 8; ++g) sid[g] = __shfl(idx, (lane & 56) + g, 64);
    bf16x8 v[8];
#pragma unroll
    for (int g = 0; g < 8; ++g)
      v[g] = *(const bf16x8*)&hb[(size_t)sid[g] * DIM + pbase];
#pragma unroll
    for (int g = 0; g < 8; ++g)
#pragma unroll
      for (int q = 0; q < 8; ++q) a[q] += (float)v[g][q];
    j += 8;
  }
  for (; j < end; ++j) {
    const int s0 = esrc[j];
    bf16x8 v0 = *(const bf16x8*)&hb[(size_t)s0 * DIM + pbase];
#pragma unroll
    for (int q = 0; q < 8; ++q) a[q] += (float)v0[q];
  }
  bf16x8 o;
#pragma unroll
  for (int q = 0; q < 8; ++q) o[q] = (__bf16)a[q];
  *(bf16x8*)&aggb[(size_t)node * DIM + pbase] = o;
}

// ---------------- 5. GEMM v7: M-only grid — cut A traffic 4x ---------------
// R14 insight: v1-v5 all ~38us because they share the SAME traffic: N-split=4
// re-reads A 4x (82 MB via L3) + 41 MB C + staging -> traffic-bound, schedule
// irrelevant. v7: grid = 313 M-blocks ONLY; each block walks all N=512.
// A read ONCE (20.5 MB); B (0.5 MB) L2-resident per XCD, staged per K-step.
// 8 waves (2M x 4N), BK=32, dbuf LDS 72 KB, both-sides XOR chunk swizzle.
__global__ __launch_bounds__(512, 2) void gemm_k(const __bf16* __restrict__ A,
                                                 const __bf16* __restrict__ B,
                                                 const float* __restrict__ bias,
                                                 const float* __restrict__ norm,
                                                 float* __restrict__ C) {
  __shared__ __bf16 As[2][64 * 32];
  __shared__ __bf16 Bs[2][512 * 32];
  const int tid = threadIdx.x;
  const int lane = tid & 63;
  const int wv = tid >> 6;          // 8 waves
  const int wm = wv >> 2;           // 0..1: 32-row half
  const int wn = wv & 3;            // 0..3: 128-col quarter
  const int m0 = blockIdx.x * 64;

  f32x4 acc[2][8] = {};

  // staging map: tid -> (row = tid>>2, chunk p = tid&3); LDS dest = tid*16 B
  // (wave-contiguous, m104-safe). Source chunk g = p ^ ((row>>2)&3) so a
  // ds_read at chunk' = c ^ ((row>>2)&3) returns global chunk c (involution).
  auto stage = [&](int buf, int kt) {
    const int kb = kt * 32;
    const int p = tid & 3;
    if (tid < 256) {                           // A: 64 rows x 32k = 256 units
      const int row = tid >> 2;
      const int g = p ^ ((row >> 2) & 3);
      int arow = m0 + row;
      arow = arow < M_NODES ? arow : (M_NODES - 1);
      async16(&As[buf][row * 32 + p * 8], A + (size_t)arow * DIM + kb + g * 8);
    }
#pragma unroll
    for (int j = 0; j < 4; ++j) {              // B: 512 rows x 32k = 2048 units
      const int row = (tid >> 2) + j * 128;
      const int g = p ^ ((row >> 2) & 3);
      async16(&Bs[buf][row * 32 + p * 8], B + (size_t)row * DIM + kb + g * 8);
    }
  };

  stage(0, 0);
  __syncthreads();

  int cur = 0;
  for (int kt = 0; kt < DIM / 32; ++kt) {      // 16 K-steps
    if (kt + 1 < DIM / 32) stage(cur ^ 1, kt + 1);
    const int c = lane >> 4;                   // k-chunk 0..3
    bf16x8 af[2], bfr[8];
#pragma unroll
    for (int m = 0; m < 2; ++m) {
      const int r = wm * 32 + m * 16 + (lane & 15);
      af[m] = *(const bf16x8*)&As[cur][r * 32 + ((c ^ ((r >> 2) & 3)) * 8)];
    }
#pragma unroll
    for (int n = 0; n < 8; ++n) {
      const int r = wn * 128 + n * 16 + (lane & 15);
      bfr[n] = *(const bf16x8*)&Bs[cur][r * 32 + ((c ^ ((r >> 2) & 3)) * 8)];
    }
#pragma unroll
    for (int m = 0; m < 2; ++m)
#pragma unroll
      for (int n = 0; n < 8; ++n)
        acc[m][n] = __builtin_amdgcn_mfma_f32_16x16x32_bf16(af[m], bfr[n], acc[m][n], 0, 0, 0);
    __syncthreads();   // drains vmcnt (next buf staged) + lgkm (cur reads done)
    cur ^= 1;
  }

  // epilogue: row = (lane>>4)*4 + r, col = lane&15 within each 16x16 frag
#pragma unroll
  for (int m = 0; m < 2; ++m) {
    const int rbase = m0 + wm * 32 + m * 16 + (lane >> 4) * 4;
#pragma unroll
    for (int r = 0; r < 4; ++r) {
      const int row = rbase + r;
      if (row < M_NODES) {
        const float nv = norm[row];
#pragma unroll
        for (int n = 0; n < 8; ++n) {
          const int col = wn * 128 + n * 16 + (lane & 15);
          float v = acc[m][n][r] * nv + bias[col];
          C[(size_t)row * DIM + col] = v > 0.f ? v : 0.f;
        }
      }
    }
  }
}

// ---------------- workspace layout ----------------
#define HB_OFF   0UL                     // 20,480,000 B  bf16 h*norm
#define AGG_OFF  20480000UL              // 20,480,000 B  bf16 aggregate
#define WT_OFF   40960000UL              //    524,288 B  bf16 W^T
#define CNT_OFF  41484288UL              //     80,000 B  counts -> cursor (16B aligned)
#define OFS_OFF  41564288UL              //     80,256 B  offsets[20001]
#define ESRC_OFF 41644544UL              //  1,280,000 B  CSR src indices
#define WS_NEEDED 42924544UL

extern "C" void kernel_launch(void* const* d_in, const int* in_sizes, int n_in,
                              void* d_out, int out_size, void* d_ws, size_t ws_size,
                              hipStream_t stream) {
  const float* h    = (const float*)d_in[0];
  const float* w    = (const float*)d_in[1];
  const float* bias = (const float*)d_in[2];
  const float* norm = (const float*)d_in[3];
  const int*   src  = (const int*)d_in[4];
  const int*   dst  = (const int*)d_in[5];
  float* out = (float*)d_out;

  if (ws_size < WS_NEEDED) return;  // clean failure signal instead of OOB

  char* ws = (char*)d_ws;
  __bf16* hb      = (__bf16*)(ws + HB_OFF);
  __bf16* aggb    = (__bf16*)(ws + AGG_OFF);
  __bf16* wT      = (__bf16*)(ws + WT_OFF);
  int*    counts  = (int*)(ws + CNT_OFF);
  int*    offsets = (int*)(ws + OFS_OFF);
  int*    esrc    = (int*)(ws + ESRC_OFF);

  zero_k<<<20, 256, 0, stream>>>((int4*)counts);
  pre_k<<<2048, 256, 0, stream>>>(h, w, norm, dst, hb, wT, counts);
  scan_k<<<1, 256, 0, stream>>>(counts, offsets);
  fill_k<<<1250, 256, 0, stream>>>(src, dst, counts, esrc);
  aggregate_k<<<5000, 256, 0, stream>>>(hb, offsets, esrc, aggb);
  gemm_k<<<313, 512, 0, stream>>>(aggb, wT, bias, norm, out);
}

// Round 16
// 120.058 us; speedup vs baseline: 1.2740x; 1.1119x over previous
//
#include <hip/hip_runtime.h>

#define M_NODES 20000
#define N_EDGES_C 320000
#define DIM 512

typedef __attribute__((ext_vector_type(4))) float f32x4;
typedef __attribute__((ext_vector_type(2))) float f32x2;
typedef __attribute__((ext_vector_type(4))) __bf16 bf16x4;
typedef __attribute__((ext_vector_type(8))) __bf16 bf16x8;

// ---------------- async global->LDS (16B per lane) ----------------
__device__ __forceinline__ void async16(__bf16* lds, const __bf16* g) {
  __builtin_amdgcn_global_load_lds(
      (const __attribute__((address_space(1))) void*)g,
      (__attribute__((address_space(3))) void*)lds, 16, 0, 0);
}

// ---------------- 0. zero counts ----------------
__global__ __launch_bounds__(256) void zero_k(int4* __restrict__ counts4) {
  const int i = blockIdx.x * 256 + threadIdx.x;
  if (i < M_NODES / 4) counts4[i] = int4{0, 0, 0, 0};
}

// ---------------- 1. pre_k: convert + W-transpose + degree count ------------
// R12 lesson: NO __threadfence (G16 fence = L2 writeback storm, ~200us).
__global__ __launch_bounds__(256) void pre_k(const float* __restrict__ h,
                                             const float* __restrict__ w,
                                             const float* __restrict__ norm,
                                             const int* __restrict__ dst,
                                             __bf16* __restrict__ hb,
                                             __bf16* __restrict__ wT,
                                             int* __restrict__ counts) {
  const int bid = blockIdx.x;
  const int tid = threadIdx.x;
  const int gtid = bid * 256 + tid;
  const int gsz = gridDim.x * 256;

  for (int i = gtid; i < M_NODES * DIM / 4; i += gsz) {
    const int elem = i * 4;
    const float s = norm[elem >> 9];
    f32x4 v = *(const f32x4*)&h[elem];
    bf16x4 o;
    o.x = (__bf16)(v.x * s);
    o.y = (__bf16)(v.y * s);
    o.z = (__bf16)(v.z * s);
    o.w = (__bf16)(v.w * s);
    *(bf16x4*)&hb[elem] = o;
  }

  if (bid < 256) {
    __shared__ float tile[32][33];
    const int bx = (bid & 15) * 32, by = (bid >> 4) * 32;
    const int tx = tid & 31, ty8 = tid >> 5;
#pragma unroll
    for (int st = 0; st < 4; ++st) {
      const int r = ty8 + st * 8;
      tile[r][tx] = w[(by + r) * DIM + bx + tx];
    }
    __syncthreads();
#pragma unroll
    for (int st = 0; st < 4; ++st) {
      const int r = ty8 + st * 8;
      wT[(bx + r) * DIM + by + tx] = (__bf16)tile[tx][r];
    }
  }

  for (int e = gtid; e < N_EDGES_C; e += gsz) atomicAdd(&counts[dst[e]], 1);
}

// ---------------- 2. scan: 1 block, 250 threads x 80 elements ----------------
__global__ __launch_bounds__(256) void scan_k(int* __restrict__ counts,
                                              int* __restrict__ offsets) {
  __shared__ int wsum2[4];
  const int tid = threadIdx.x;
  const int lane = tid & 63, wid = tid >> 6;
  const int base = tid * 80;
  int s = 0;
  if (tid < 250) {
#pragma unroll
    for (int i = 0; i < 80; i += 4) {
      int4 c = *(const int4*)&counts[base + i];
      s += c.x + c.y + c.z + c.w;
    }
  }
  int x = s;
#pragma unroll
  for (int off = 1; off < 64; off <<= 1) {
    int t = __shfl_up(x, off, 64);
    if (lane >= off) x += t;
  }
  if (lane == 63) wsum2[wid] = x;
  __syncthreads();
  int wbase = 0;
  for (int wI = 0; wI < wid; ++wI) wbase += wsum2[wI];
  int run = wbase + x - s;
  if (tid < 250) {
#pragma unroll
    for (int i = 0; i < 80; i += 4) {
      int4 c = *(const int4*)&counts[base + i];
      int4 o;
      o.x = run;
      o.y = run + c.x;
      o.z = o.y + c.y;
      o.w = o.z + c.z;
      *(int4*)&offsets[base + i] = o;
      *(int4*)&counts[base + i] = o;       // counts becomes fill cursor
      run = o.w + c.w;
    }
  }
  if (tid == 0) {
    int tot = 0;
#pragma unroll
    for (int wI = 0; wI < 4; ++wI) tot += wsum2[wI];
    offsets[M_NODES] = tot;
  }
}

// ---------------- 3. CSR fill ----------------
__global__ __launch_bounds__(256) void fill_k(const int* __restrict__ src,
                                              const int* __restrict__ dst,
                                              int* __restrict__ cursor,
                                              int* __restrict__ esrc) {
  int e = blockIdx.x * 256 + threadIdx.x;
  if (e < N_EDGES_C) {
    int p = atomicAdd(&cursor[dst[e]], 1);
    esrc[p] = src[e];
  }
}

// ---------------- 4. aggregate: XCD-pinned panels + bit-trick unpack --------
// This round's experiment: replace per-element (float)bf16 cvt+add (2 instr/
// col) with uint bit-unpack (u<<16 / u&0xFFFF0000 — bit-exact same f32) into
// float2 accumulators, enabling v_pk_add_f32 pair formation. Structure
// (panels, 8-wide idx broadcast) unchanged.
__global__ __launch_bounds__(256) void aggregate_k(const __bf16* __restrict__ hb,
                                                   const int* __restrict__ offs,
                                                   const int* __restrict__ esrc,
                                                   __bf16* __restrict__ aggb) {
  const int panel = blockIdx.x & 7;           // -> XCD id (round-robin dispatch)
  const int nb = blockIdx.x >> 3;             // 0..624
  const int wv = threadIdx.x >> 6;
  const int lane = threadIdx.x & 63;
  const int slot = lane >> 3;                 // 0..7: node sub-index within wave
  const int cg = lane & 7;                    // 0..7: column group (8 cols)
  const int node = nb * 32 + wv * 8 + slot;   // 625*32 = 20000 exactly

  const int beg = offs[node], end = offs[node + 1];
  const size_t pbase = (size_t)panel * 64 + cg * 8;

  f32x2 a2[4] = {};
  int j = beg;
  while (j + 8 <= end) {
    const int idx = esrc[j + cg];             // 8 consecutive indices per group
    int sid[8];
#pragma unroll
    for (int g = 0; g < 8; ++g) sid[g] = __shfl(idx, (lane & 56) + g, 64);
#pragma unroll
    for (int g = 0; g < 8; ++g) {
      const uint4 u = *(const uint4*)&hb[(size_t)sid[g] * DIM + pbase];
      f32x2 p0 = {__uint_as_float(u.x << 16), __uint_as_float(u.x & 0xFFFF0000u)};
      f32x2 p1 = {__uint_as_float(u.y << 16), __uint_as_float(u.y & 0xFFFF0000u)};
      f32x2 p2 = {__uint_as_float(u.z << 16), __uint_as_float(u.z & 0xFFFF0000u)};
      f32x2 p3 = {__uint_as_float(u.w << 16), __uint_as_float(u.w & 0xFFFF0000u)};
      a2[0] += p0; a2[1] += p1; a2[2] += p2; a2[3] += p3;
    }
    j += 8;
  }
  for (; j < end; ++j) {
    const uint4 u = *(const uint4*)&hb[(size_t)esrc[j] * DIM + pbase];
    f32x2 p0 = {__uint_as_float(u.x << 16), __uint_as_float(u.x & 0xFFFF0000u)};
    f32x2 p1 = {__uint_as_float(u.y << 16), __uint_as_float(u.y & 0xFFFF0000u)};
    f32x2 p2 = {__uint_as_float(u.z << 16), __uint_as_float(u.z & 0xFFFF0000u)};
    f32x2 p3 = {__uint_as_float(u.w << 16), __uint_as_float(u.w & 0xFFFF0000u)};
    a2[0] += p0; a2[1] += p1; a2[2] += p2; a2[3] += p3;
  }
  bf16x8 o;
#pragma unroll
  for (int q = 0; q < 4; ++q) {
    o[2 * q]     = (__bf16)a2[q].x;
    o[2 * q + 1] = (__bf16)a2[q].y;
  }
  *(bf16x8*)&aggb[(size_t)node * DIM + pbase] = o;
}

// ---------------- 5. GEMM v5 (REVERT to best-measured R11/R13 config) -------
// v1-v7 all land 38-43us: latency/issue plateau, not schedule/traffic/
// occupancy-bound (v4 occupancy-fix null, v5 counted-vmcnt null-vs-v1,
// v6 LDS-free -65% worse, v7 traffic-cut -13% worse). v5 = best total.
__global__ __launch_bounds__(256, 2) void gemm_k(const __bf16* __restrict__ A,
                                                 const __bf16* __restrict__ B,
                                                 const float* __restrict__ bias,
                                                 const float* __restrict__ norm,
                                                 float* __restrict__ C) {
  __shared__ __bf16 As[3][64 * 64];
  __shared__ __bf16 Bs[3][128 * 64];
  const int tid = threadIdx.x;
  const int lane = tid & 63;
  const int wv = tid >> 6;          // 4 waves: wr in {0,1} x wc in {0,1}
  const int wr = wv >> 1, wc = wv & 1;
  const int m0 = blockIdx.x * 64;
  const int n0 = blockIdx.y * 128;

  f32x4 acc[2][4] = {};

  const int srow = tid >> 3;                      // 0..31: row in 32-row strip
  const int scol = ((tid & 7) ^ (srow & 7)) * 8;  // pre-swizzled source chunk
  const int ldst = (tid & 7) * 8;                 // linear LDS dest chunk

  auto stage = [&](int buf, int kt) {
    const int kb = kt * 64 + scol;
#pragma unroll
    for (int jj = 0; jj < 2; ++jj) {              // A: 64 rows
      const int lrow = jj * 32 + srow;
      int arow = m0 + lrow;
      arow = arow < M_NODES ? arow : (M_NODES - 1);   // clamp tail rows
      async16(&As[buf][lrow * 64 + ldst], A + (size_t)arow * DIM + kb);
    }
#pragma unroll
    for (int jj = 0; jj < 4; ++jj) {              // B: 128 rows (in range)
      const int lrow = jj * 32 + srow;
      async16(&Bs[buf][lrow * 64 + ldst], B + (size_t)(n0 + lrow) * DIM + kb);
    }
  };

  stage(0, 0);
  stage(1, 1);                                    // 12 loads in flight

  int cb = 0;                                     // compute buffer = kt % 3
  for (int kt = 0; kt < DIM / 64; ++kt) {
    if (kt < DIM / 64 - 1)
      asm volatile("s_waitcnt vmcnt(6)" ::: "memory");  // oldest 6 (buf cb) done
    else
      asm volatile("s_waitcnt vmcnt(0)" ::: "memory");  // final drain
    __builtin_amdgcn_s_barrier();
    asm volatile("" ::: "memory");

    if (kt + 2 < DIM / 64) {
      int sb = cb + 2; if (sb >= 3) sb -= 3;
      stage(sb, kt + 2);                          // refill: back to 12 in flight
    }

#pragma unroll
    for (int kk = 0; kk < 64; kk += 32) {
      const int c = (kk >> 3) + (lane >> 4);      // 16B chunk index
      bf16x8 af[2], bfr[4];
#pragma unroll
      for (int m = 0; m < 2; ++m) {
        const int r = wr * 32 + m * 16 + (lane & 15);
        af[m] = *(const bf16x8*)&As[cb][r * 64 + ((c ^ (r & 7)) * 8)];
      }
#pragma unroll
      for (int n = 0; n < 4; ++n) {
        const int r = wc * 64 + n * 16 + (lane & 15);
        bfr[n] = *(const bf16x8*)&Bs[cb][r * 64 + ((c ^ (r & 7)) * 8)];
      }
#pragma unroll
      for (int m = 0; m < 2; ++m)
#pragma unroll
        for (int n = 0; n < 4; ++n)
          acc[m][n] = __builtin_amdgcn_mfma_f32_16x16x32_bf16(af[m], bfr[n], acc[m][n], 0, 0, 0);
    }
    cb = (cb == 2) ? 0 : cb + 1;
  }

  // epilogue: C row = (lane>>4)*4 + reg, col = lane&15 within each 16x16 frag
#pragma unroll
  for (int m = 0; m < 2; ++m) {
    const int rbase = m0 + wr * 32 + m * 16 + (lane >> 4) * 4;
#pragma unroll
    for (int r = 0; r < 4; ++r) {
      const int row = rbase + r;
      if (row < M_NODES) {
        const float nv = norm[row];
#pragma unroll
        for (int n = 0; n < 4; ++n) {
          const int col = n0 + wc * 64 + n * 16 + (lane & 15);
          float v = acc[m][n][r] * nv + bias[col];
          C[(size_t)row * DIM + col] = v > 0.f ? v : 0.f;
        }
      }
    }
  }
}

// ---------------- workspace layout ----------------
#define HB_OFF   0UL                     // 20,480,000 B  bf16 h*norm
#define AGG_OFF  20480000UL              // 20,480,000 B  bf16 aggregate
#define WT_OFF   40960000UL              //    524,288 B  bf16 W^T
#define CNT_OFF  41484288UL              //     80,000 B  counts -> cursor (16B aligned)
#define OFS_OFF  41564288UL              //     80,256 B  offsets[20001]
#define ESRC_OFF 41644544UL              //  1,280,000 B  CSR src indices
#define WS_NEEDED 42924544UL

extern "C" void kernel_launch(void* const* d_in, const int* in_sizes, int n_in,
                              void* d_out, int out_size, void* d_ws, size_t ws_size,
                              hipStream_t stream) {
  const float* h    = (const float*)d_in[0];
  const float* w    = (const float*)d_in[1];
  const float* bias = (const float*)d_in[2];
  const float* norm = (const float*)d_in[3];
  const int*   src  = (const int*)d_in[4];
  const int*   dst  = (const int*)d_in[5];
  float* out = (float*)d_out;

  if (ws_size < WS_NEEDED) return;  // clean failure signal instead of OOB

  char* ws = (char*)d_ws;
  __bf16* hb      = (__bf16*)(ws + HB_OFF);
  __bf16* aggb    = (__bf16*)(ws + AGG_OFF);
  __bf16* wT      = (__bf16*)(ws + WT_OFF);
  int*    counts  = (int*)(ws + CNT_OFF);
  int*    offsets = (int*)(ws + OFS_OFF);
  int*    esrc    = (int*)(ws + ESRC_OFF);

  zero_k<<<20, 256, 0, stream>>>((int4*)counts);
  pre_k<<<2048, 256, 0, stream>>>(h, w, norm, dst, hb, wT, counts);
  scan_k<<<1, 256, 0, stream>>>(counts, offsets);
  fill_k<<<1250, 256, 0, stream>>>(src, dst, counts, esrc);
  aggregate_k<<<5000, 256, 0, stream>>>(hb, offsets, esrc, aggb);
  gemm_k<<<dim3(313, 4), 256, 0, stream>>>(aggb, wT, bias, norm, out);
}